// Round 10
// baseline (749.744 us; speedup 1.0000x reference)
//
#include <hip/hip_runtime.h>

#define NP 50000
#define NA 20000
#define EW 400000
#define EC 800000
#define ER 400000

// ---------------------------------------------------------------- prep
__global__ __launch_bounds__(256) void prep_k(
    const float* __restrict__ Wr0w, const float* __restrict__ Wr0c,
    const float* __restrict__ bl0w, const float* __restrict__ bl0c,
    const float* __restrict__ Wr1w, const float* __restrict__ Wr1c,
    const float* __restrict__ bl1w, const float* __restrict__ bl1c,
    float* __restrict__ Wr0wc, float* __restrict__ b0p,
    float* __restrict__ Wr1wc, float* __restrict__ b1p)
{
    int i = blockIdx.x * 256 + threadIdx.x;
    if (i < 128*128) Wr0wc[i] = Wr0w[i] + Wr0c[i];
    if (i < 128*40)  Wr1wc[i] = Wr1w[i] + Wr1c[i];
    if (i < 128)     b0p[i] = 0.5f*(bl0w[i] + bl0c[i]);
    if (i < 40)      b1p[i] = 0.5f*(bl1w[i] + bl1c[i]);
}

// ---------------------------------------------------------------- degree histograms (all 3 relations)
__global__ __launch_bounds__(256) void count_all_k(
    const int* __restrict__ ei_w, const int* __restrict__ ei_c, const int* __restrict__ ei_r,
    int* __restrict__ cntw, int* __restrict__ cntc, int* __restrict__ cntr)
{
    int i = blockIdx.x * 256 + threadIdx.x;
    if (i < EW)              atomicAdd(&cntw[ei_w[EW + i]], 1);
    else if (i < EW+EC)      atomicAdd(&cntc[ei_c[EC + (i-EW)]], 1);
    else if (i < EW+EC+ER)   atomicAdd(&cntr[ei_r[ER + (i-EW-EC)]], 1);
}

// ---------------------------------------------------------------- 3 exclusive scans, shfl-based
// 4 elems/thread, 4 barriers per 4096-chunk (vs ~20/1024-chunk Hillis-Steele)
__global__ __launch_bounds__(1024) void scan3_k(
    const int* __restrict__ c0, int n0, int* __restrict__ o0,
    const int* __restrict__ c1, int n1, int* __restrict__ o1,
    const int* __restrict__ c2, int n2, int* __restrict__ o2)
{
    __shared__ int wsum[16];
    __shared__ int carry_s;
    const int* cnt; int n; int* off;
    if (blockIdx.x == 0)      { cnt = c0; n = n0; off = o0; }
    else if (blockIdx.x == 1) { cnt = c1; n = n1; off = o1; }
    else                      { cnt = c2; n = n2; off = o2; }
    const int tid  = threadIdx.x;
    const int lane = tid & 63;
    const int wid  = tid >> 6;
    if (tid == 0) carry_s = 0;
    __syncthreads();
    const int CH = 4096;
    const int nchunk = (n + CH - 1) / CH;
    for (int c = 0; c < nchunk; ++c) {
        int base = c*CH + tid*4;
        int4 v = make_int4(0,0,0,0);
        if (base + 3 < n) v = *reinterpret_cast<const int4*>(cnt + base);
        else {
            if (base   < n) v.x = cnt[base];
            if (base+1 < n) v.y = cnt[base+1];
            if (base+2 < n) v.z = cnt[base+2];
            if (base+3 < n) v.w = cnt[base+3];
        }
        int s1 = v.x + v.y, s2 = s1 + v.z, s3 = s2 + v.w;  // thread-inclusive
        int x = s3;
#pragma unroll
        for (int d = 1; d < 64; d <<= 1) {                 // wave inclusive scan
            int u = __shfl_up(x, d, 64);
            if (lane >= d) x += u;
        }
        if (lane == 63) wsum[wid] = x;
        int texc = x - s3;                                 // exclusive within wave
        __syncthreads();
        if (wid == 0 && lane < 16) {                       // cross-wave scan (16 totals)
            int y = wsum[lane];
#pragma unroll
            for (int d = 1; d < 16; d <<= 1) {
                int u = __shfl_up(y, d, 16);
                if (lane >= d) y += u;
            }
            wsum[lane] = y;                                // inclusive
        }
        __syncthreads();
        int carry = carry_s;
        int wexc  = wid ? wsum[wid-1] : 0;
        int pre   = carry + wexc + texc;
        int4 ov = make_int4(pre, pre + v.x, pre + s1, pre + s2);
        if (base + 3 < n) *reinterpret_cast<int4*>(off + base) = ov;
        else {
            if (base   < n) off[base]   = ov.x;
            if (base+1 < n) off[base+1] = ov.y;
            if (base+2 < n) off[base+2] = ov.z;
            if (base+3 < n) off[base+3] = ov.w;
        }
        __syncthreads();
        if (tid == 0) carry_s += wsum[15];
        __syncthreads();
    }
    if (tid == 0) off[n] = carry_s;
}

// ---------------------------------------------------------------- adjacency fill (all 3; consumes cnt)
__global__ __launch_bounds__(256) void fill_all_k(
    const int* __restrict__ ei_w, const int* __restrict__ ei_c, const int* __restrict__ ei_r,
    const int* __restrict__ offw, const int* __restrict__ offc, const int* __restrict__ offr,
    int* __restrict__ cntw, int* __restrict__ cntc, int* __restrict__ cntr,
    int* __restrict__ adjw, int* __restrict__ adjc, int* __restrict__ adjr)
{
    int i = blockIdx.x * 256 + threadIdx.x;
    const int* ei; const int* off; int* cnt; int* adj; int e; int E;
    if (i < EW)            { e = i;        ei = ei_w; off = offw; cnt = cntw; adj = adjw; E = EW; }
    else if (i < EW+EC)    { e = i-EW;     ei = ei_c; off = offc; cnt = cntc; adj = adjc; E = EC; }
    else if (i < EW+EC+ER) { e = i-EW-EC;  ei = ei_r; off = offr; cnt = cntr; adj = adjr; E = ER; }
    else return;
    int d = ei[E + e];
    int p = atomicSub(&cnt[d], 1) - 1;
    adj[off[d] + p] = ei[e];
}

// ---------------------------------------------------------------- gather-mean D=128, all 3 relations
__global__ __launch_bounds__(256) void gather128_all_k(
    const float* __restrict__ x_paper, const float* __restrict__ x_author,
    const int* __restrict__ offw, const int* __restrict__ adjw, float* __restrict__ aggw,
    const int* __restrict__ offc, const int* __restrict__ adjc, float* __restrict__ aggc,
    const int* __restrict__ offr, const int* __restrict__ adjr, float* __restrict__ aggr)
{
    int W    = blockIdx.x * 4 + (threadIdx.x >> 6);
    int lane = threadIdx.x & 63;
    const float* X; const int* off; const int* adj; float* AGG; int w;
    if (W < NP)          { w = W;        X = x_author; off = offw; adj = adjw; AGG = aggw; }
    else if (W < 2*NP)   { w = W - NP;   X = x_paper;  off = offc; adj = adjc; AGG = aggc; }
    else if (W < 2*NP+NA){ w = W - 2*NP; X = x_paper;  off = offr; adj = adjr; AGG = aggr; }
    else return;
    int b = off[w], e = off[w+1];
    float2 acc = make_float2(0.f, 0.f);
    for (int j0 = b; j0 < e; j0 += 64) {
        int sl = (j0 + lane < e) ? adj[j0 + lane] : 0;
        int m  = min(64, e - j0);
        for (int k = 0; k < m; ++k) {
            int s = __shfl(sl, k, 64);
            float2 v = reinterpret_cast<const float2*>(X + (size_t)s * 128)[lane];
            acc.x += v.x; acc.y += v.y;
        }
    }
    float sc = 1.0f / fmaxf((float)(e - b), 1.0f);
    reinterpret_cast<float2*>(AGG + (size_t)w * 128)[lane] = make_float2(acc.x*sc, acc.y*sc);
}

// ---------------------------------------------------------------- fused multi-part GEMM, N=128
// C = relu?(alpha * sum_p(Ap @ Bp) + bias); reg-staged double buffer (prefetch
// next tile into VGPRs during compute; +32 VGPR, LDS stays 32 KB)
__device__ __forceinline__ void fma4(float4& c, float a, const float4& b) {
    c.x += a*b.x; c.y += a*b.y; c.z += a*b.z; c.w += a*b.w;
}

__global__ __launch_bounds__(256) void gemmf_k(
    const float* __restrict__ A0, const float* __restrict__ A1, const float* __restrict__ A2,
    const float* __restrict__ B0, const float* __restrict__ B1, const float* __restrict__ B2,
    float* __restrict__ C, int M, int nparts, float alpha,
    const float* __restrict__ bias, int relu)
{
    __shared__ float As[32][128];   // k-major (transposed)  16 KB
    __shared__ float Bs[32][128];   // k-major (natural)     16 KB
    const int tid  = threadIdx.x;
    const int row0 = blockIdx.x * 128;
    const int tx = tid & 15;
    const int ty = tid >> 4;

    float4 acc[2][2][4];
#pragma unroll
    for (int rh = 0; rh < 2; ++rh)
#pragma unroll
        for (int ch = 0; ch < 2; ++ch)
#pragma unroll
            for (int i = 0; i < 4; ++i) acc[rh][ch][i] = make_float4(0.f,0.f,0.f,0.f);

    const int KT = nparts * 4;
    float4 ra[4], rb[4];

    auto loadT = [&](int kt) {
        const int p  = kt >> 2;
        const int cb = (kt & 3) * 32;
        const float* Ap = (p == 0) ? A0 : (p == 1) ? A1 : A2;
        const float* Bp = (p == 0) ? B0 : (p == 1) ? B1 : B2;
#pragma unroll
        for (int i = 0; i < 4; ++i) {
            int idx = tid + i*256;
            int m = idx & 127, kq = idx >> 7;
            int row = row0 + m;
            ra[i] = make_float4(0.f,0.f,0.f,0.f);
            if (row < M) ra[i] = *reinterpret_cast<const float4*>(Ap + (size_t)row*128 + cb + kq*4);
            int n4 = idx & 31, k = idx >> 5;
            rb[i] = *reinterpret_cast<const float4*>(Bp + (size_t)(cb + k)*128 + n4*4);
        }
    };
    auto writeT = [&]() {
#pragma unroll
        for (int i = 0; i < 4; ++i) {
            int idx = tid + i*256;
            int m = idx & 127, kq = idx >> 7;
            As[kq*4+0][m] = ra[i].x; As[kq*4+1][m] = ra[i].y;
            As[kq*4+2][m] = ra[i].z; As[kq*4+3][m] = ra[i].w;
            int n4 = idx & 31, k = idx >> 5;
            *reinterpret_cast<float4*>(&Bs[k][n4*4]) = rb[i];
        }
    };

    loadT(0);
    writeT();
    __syncthreads();
    for (int kt = 0; kt < KT; ++kt) {
        if (kt + 1 < KT) loadT(kt + 1);       // global loads in flight during compute
#pragma unroll 8
        for (int k = 0; k < 32; ++k) {
            float4 a0 = *reinterpret_cast<const float4*>(&As[k][ty*4]);
            float4 a1 = *reinterpret_cast<const float4*>(&As[k][64 + ty*4]);
            float4 b0 = *reinterpret_cast<const float4*>(&Bs[k][tx*4]);
            float4 b1 = *reinterpret_cast<const float4*>(&Bs[k][64 + tx*4]);
#pragma unroll
            for (int i = 0; i < 4; ++i) {
                float av = (&a0.x)[i];
                fma4(acc[0][0][i], av, b0);
                fma4(acc[0][1][i], av, b1);
            }
#pragma unroll
            for (int i = 0; i < 4; ++i) {
                float av = (&a1.x)[i];
                fma4(acc[1][0][i], av, b0);
                fma4(acc[1][1][i], av, b1);
            }
        }
        if (kt + 1 < KT) {
            __syncthreads();
            writeT();
            __syncthreads();
        }
    }

#pragma unroll
    for (int rh = 0; rh < 2; ++rh)
#pragma unroll
        for (int i = 0; i < 4; ++i) {
            int row = row0 + rh*64 + ty*4 + i;
            if (row >= M) continue;
#pragma unroll
            for (int ch = 0; ch < 2; ++ch) {
                int col = ch*64 + tx*4;
                float4 t = acc[rh][ch][i];
                float4 bb = *reinterpret_cast<const float4*>(&bias[col]);
                t.x = alpha*t.x + bb.x; t.y = alpha*t.y + bb.y;
                t.z = alpha*t.z + bb.z; t.w = alpha*t.w + bb.w;
                if (relu) {
                    t.x = fmaxf(t.x, 0.f); t.y = fmaxf(t.y, 0.f);
                    t.z = fmaxf(t.z, 0.f); t.w = fmaxf(t.w, 0.f);
                }
                *reinterpret_cast<float4*>(C + (size_t)row*128 + col) = t;
            }
        }
}

// ---------------------------------------------------------------- GEMM K=128, N=40 (single B)
__global__ __launch_bounds__(256) void gemm40_k(
    const float* __restrict__ A, const float* __restrict__ B, float* __restrict__ C, int M)
{
    __shared__ float Bs[128][40];   // 20 KB
    __shared__ float As[24][128];   // 12 KB
    const int tid  = threadIdx.x;
    const int row0 = blockIdx.x * 24;

#pragma unroll
    for (int i = 0; i < 5; ++i) {
        int idx = tid + i*256;
        reinterpret_cast<float4*>(&Bs[0][0])[idx] = reinterpret_cast<const float4*>(B)[idx];
    }
#pragma unroll
    for (int i = 0; i < 3; ++i) {
        int idx = tid + i*256;
        int r = idx >> 5, c4 = idx & 31;
        int row = row0 + r;
        float4 v = make_float4(0.f,0.f,0.f,0.f);
        if (row < M) v = reinterpret_cast<const float4*>(A + (size_t)row*128)[c4];
        reinterpret_cast<float4*>(&As[r][0])[c4] = v;
    }
    __syncthreads();

    if (tid < 240) {
        int col  = tid % 40;
        int rsub = tid / 40;
        float a0=0.f, a1=0.f, a2=0.f, a3=0.f;
        for (int k = 0; k < 128; ++k) {
            float b = Bs[k][col];
            a0 += As[rsub*4+0][k]*b;
            a1 += As[rsub*4+1][k]*b;
            a2 += As[rsub*4+2][k]*b;
            a3 += As[rsub*4+3][k]*b;
        }
        int rb = row0 + rsub*4;
        if (rb+0 < M) C[(size_t)(rb+0)*40 + col] = a0;
        if (rb+1 < M) C[(size_t)(rb+1)*40 + col] = a1;
        if (rb+2 < M) C[(size_t)(rb+2)*40 + col] = a2;
        if (rb+3 < M) C[(size_t)(rb+3)*40 + col] = a3;
    }
}

// ---------------------------------------------------------------- dual-B GEMM K=128, N=40
__global__ __launch_bounds__(256) void gemm40x2_k(
    const float* __restrict__ A, const float* __restrict__ B1, const float* __restrict__ B2,
    float* __restrict__ C1, float* __restrict__ C2, int M)
{
    __shared__ float Bs1[128][40];  // 20 KB
    __shared__ float Bs2[128][40];  // 20 KB
    __shared__ float As[24][128];   // 12 KB
    const int tid  = threadIdx.x;
    const int row0 = blockIdx.x * 24;

#pragma unroll
    for (int i = 0; i < 5; ++i) {
        int idx = tid + i*256;
        reinterpret_cast<float4*>(&Bs1[0][0])[idx] = reinterpret_cast<const float4*>(B1)[idx];
        reinterpret_cast<float4*>(&Bs2[0][0])[idx] = reinterpret_cast<const float4*>(B2)[idx];
    }
#pragma unroll
    for (int i = 0; i < 3; ++i) {
        int idx = tid + i*256;
        int r = idx >> 5, c4 = idx & 31;
        int row = row0 + r;
        float4 v = make_float4(0.f,0.f,0.f,0.f);
        if (row < M) v = reinterpret_cast<const float4*>(A + (size_t)row*128)[c4];
        reinterpret_cast<float4*>(&As[r][0])[c4] = v;
    }
    __syncthreads();

    if (tid < 240) {
        int col  = tid % 40;
        int rsub = tid / 40;
        float p0=0.f,p1=0.f,p2=0.f,p3=0.f;
        float q0=0.f,q1=0.f,q2=0.f,q3=0.f;
        for (int k = 0; k < 128; ++k) {
            float b1 = Bs1[k][col];
            float b2 = Bs2[k][col];
            float v0 = As[rsub*4+0][k], v1 = As[rsub*4+1][k];
            float v2 = As[rsub*4+2][k], v3 = As[rsub*4+3][k];
            p0 += v0*b1; p1 += v1*b1; p2 += v2*b1; p3 += v3*b1;
            q0 += v0*b2; q1 += v1*b2; q2 += v2*b2; q3 += v3*b2;
        }
        int rb = row0 + rsub*4;
        if (rb+0 < M) { C1[(size_t)(rb+0)*40 + col] = p0; C2[(size_t)(rb+0)*40 + col] = q0; }
        if (rb+1 < M) { C1[(size_t)(rb+1)*40 + col] = p1; C2[(size_t)(rb+1)*40 + col] = q1; }
        if (rb+2 < M) { C1[(size_t)(rb+2)*40 + col] = p2; C2[(size_t)(rb+2)*40 + col] = q2; }
        if (rb+3 < M) { C1[(size_t)(rb+3)*40 + col] = p3; C2[(size_t)(rb+3)*40 + col] = q3; }
    }
}

// ---------------------------------------------------------------- fused layer-1 gather + combine
__global__ __launch_bounds__(256) void gather40f_k(
    const float* __restrict__ T1w, const float* __restrict__ T1c,
    const int* __restrict__ offw, const int* __restrict__ adjw,
    const int* __restrict__ offc, const int* __restrict__ adjc,
    const float* __restrict__ b1p, float* __restrict__ out)
{
    int w    = blockIdx.x * 4 + (threadIdx.x >> 6);
    int lane = threadIdx.x & 63;
    if (w >= NP) return;
    const bool act = lane < 40;

    float aw = 0.f;
    {
        int b = offw[w], e = offw[w+1];
        for (int j0 = b; j0 < e; j0 += 64) {
            int sl = (j0 + lane < e) ? adjw[j0 + lane] : 0;
            int m  = min(64, e - j0);
            for (int k = 0; k < m; ++k) {
                int s = __shfl(sl, k, 64);
                if (act) aw += T1w[(size_t)s * 40 + lane];
            }
        }
        aw *= 1.0f / fmaxf((float)(e - b), 1.0f);
    }
    float ac = 0.f;
    {
        int b = offc[w], e = offc[w+1];
        for (int j0 = b; j0 < e; j0 += 64) {
            int sl = (j0 + lane < e) ? adjc[j0 + lane] : 0;
            int m  = min(64, e - j0);
            for (int k = 0; k < m; ++k) {
                int s = __shfl(sl, k, 64);
                if (act) ac += T1c[(size_t)s * 40 + lane];
            }
        }
        ac *= 1.0f / fmaxf((float)(e - b), 1.0f);
    }
    if (act) {
        size_t idx = (size_t)w * 40 + lane;
        out[idx] = 0.5f*(aw + ac + out[idx]) + b1p[lane];
    }
}

// ---------------------------------------------------------------- launch
extern "C" void kernel_launch(void* const* d_in, const int* in_sizes, int n_in,
                              void* d_out, int out_size, void* d_ws, size_t ws_size,
                              hipStream_t stream)
{
    (void)in_sizes; (void)n_in; (void)out_size; (void)ws_size;

    const float* x_paper  = (const float*)d_in[0];
    const float* x_author = (const float*)d_in[1];
    const int*   ei_w     = (const int*)d_in[2];
    const int*   ei_c     = (const int*)d_in[3];
    const int*   ei_r     = (const int*)d_in[4];
    const float* Wl0w = (const float*)d_in[5];
    const float* bl0w = (const float*)d_in[6];
    const float* Wr0w = (const float*)d_in[7];
    const float* Wl0c = (const float*)d_in[8];
    const float* bl0c = (const float*)d_in[9];
    const float* Wr0c = (const float*)d_in[10];
    const float* Wl0r = (const float*)d_in[11];
    const float* bl0r = (const float*)d_in[12];
    const float* Wr0r = (const float*)d_in[13];
    const float* Wl1w = (const float*)d_in[14];
    const float* bl1w = (const float*)d_in[15];
    const float* Wr1w = (const float*)d_in[16];
    const float* Wl1c = (const float*)d_in[17];
    const float* bl1c = (const float*)d_in[18];
    const float* Wr1c = (const float*)d_in[19];
    // d_in[20..22] = Wl1_r / bl1_r / Wr1_r: dead (layer-1 author output unused)
    float* out = (float*)d_out;

    float* ws = (float*)d_ws;
    size_t o = 0;
    int* cntw = (int*)(ws + o); o += NP;        // int4-aligned (NP*4 % 16 == 0)
    int* cntc = (int*)(ws + o); o += NP;
    int* cntr = (int*)(ws + o); o += NA;
    const size_t zeroInts = o;                  // memset region (cnt/cursor)
    int* offw = (int*)(ws + o); o += NP + 4;    // +4 pad keeps int4 alignment
    int* offc = (int*)(ws + o); o += NP + 4;
    int* offr = (int*)(ws + o); o += NA + 4;
    int* adjw = (int*)(ws + o); o += EW;
    int* adjc = (int*)(ws + o); o += EC;
    int* adjr = (int*)(ws + o); o += ER;
    float* aggw = ws + o; o += (size_t)NP*128;
    float* aggc = ws + o; o += (size_t)NP*128;
    float* aggr = ws + o; o += (size_t)NA*128;
    float* hp1  = ws + o; o += (size_t)NP*128;
    float* ha1  = ws + o; o += (size_t)NA*128;
    float* Wr0wc = ws + o; o += 128*128;
    float* b0p   = ws + o; o += 128;
    float* Wr1wc = ws + o; o += 128*40;
    float* b1p   = ws + o; o += 40;
    // aliases (aggw free after paper gemmf)
    float* T1w   = aggw;                 // NA*40
    float* T1c   = aggw + (size_t)NA*40; // NP*40  (2.8M floats <= NP*128)

    hipMemsetAsync(d_ws, 0, zeroInts * sizeof(int), stream);

    prep_k<<<64, 256, 0, stream>>>(Wr0w, Wr0c, bl0w, bl0c, Wr1w, Wr1c, bl1w, bl1c,
                                   Wr0wc, b0p, Wr1wc, b1p);

    // CSR build (per call; ws is re-poisoned between calls)
    count_all_k<<<(EW+EC+ER+255)/256, 256, 0, stream>>>(ei_w, ei_c, ei_r, cntw, cntc, cntr);
    scan3_k<<<3, 1024, 0, stream>>>(cntw, NP, offw, cntc, NP, offc, cntr, NA, offr);
    fill_all_k<<<(EW+EC+ER+255)/256, 256, 0, stream>>>(ei_w, ei_c, ei_r, offw, offc, offr,
                                                       cntw, cntc, cntr, adjw, adjc, adjr);

    // layer 0: gather-mean of raw features (D=128), all 3 relations, mean folded in
    gather128_all_k<<<(2*NP+NA+3)/4, 256, 0, stream>>>(x_paper, x_author,
                                                       offw, adjw, aggw,
                                                       offc, adjc, aggc,
                                                       offr, adjr, aggr);

    // hp1 = relu(0.5*(xp@Wr0wc + mw@Wl0w + mc@Wl0c) + b0p)   [K=384 fused]
    gemmf_k<<<(NP+127)/128, 256, 0, stream>>>(x_paper, aggw, aggc, Wr0wc, Wl0w, Wl0c,
                                              hp1, NP, 3, 0.5f, b0p, 1);
    // ha1 = relu(xa@Wr0r + mr@Wl0r + bl0r)                    [K=256 fused]
    gemmf_k<<<(NA+127)/128, 256, 0, stream>>>(x_author, aggr, nullptr, Wr0r, Wl0r, nullptr,
                                              ha1, NA, 2, 1.0f, bl0r, 1);

    // layer 1: transform first (40 dims), then gather
    gemm40_k  <<<(NA+23)/24, 256, 0, stream>>>(ha1, Wl1w, T1w, NA);
    gemm40x2_k<<<(NP+23)/24, 256, 0, stream>>>(hp1, Wl1c, Wr1wc, T1c, out, NP);

    // fused: out = 0.5*(mean_w(T1w) + mean_c(T1c) + out) + b1p
    gather40f_k<<<(NP+3)/4, 256, 0, stream>>>(T1w, T1c, offw, adjw, offc, adjc, b1p, out);
}

// Round 11
// 740.792 us; speedup vs baseline: 1.0121x; 1.0121x over previous
//
#include <hip/hip_runtime.h>

#define NP 50000
#define NA 20000
#define EW 400000
#define EC 800000
#define ER 400000

// ---------------------------------------------------------------- prep
__global__ __launch_bounds__(256) void prep_k(
    const float* __restrict__ Wr0w, const float* __restrict__ Wr0c,
    const float* __restrict__ bl0w, const float* __restrict__ bl0c,
    const float* __restrict__ Wr1w, const float* __restrict__ Wr1c,
    const float* __restrict__ bl1w, const float* __restrict__ bl1c,
    float* __restrict__ Wr0wc, float* __restrict__ b0p,
    float* __restrict__ Wr1wc, float* __restrict__ b1p)
{
    int i = blockIdx.x * 256 + threadIdx.x;
    if (i < 128*128) Wr0wc[i] = Wr0w[i] + Wr0c[i];
    if (i < 128*40)  Wr1wc[i] = Wr1w[i] + Wr1c[i];
    if (i < 128)     b0p[i] = 0.5f*(bl0w[i] + bl0c[i]);
    if (i < 40)      b1p[i] = 0.5f*(bl1w[i] + bl1c[i]);
}

// ---------------------------------------------------------------- degree histograms (all 3 relations)
__global__ __launch_bounds__(256) void count_all_k(
    const int* __restrict__ ei_w, const int* __restrict__ ei_c, const int* __restrict__ ei_r,
    int* __restrict__ cntw, int* __restrict__ cntc, int* __restrict__ cntr)
{
    int i = blockIdx.x * 256 + threadIdx.x;
    if (i < EW)              atomicAdd(&cntw[ei_w[EW + i]], 1);
    else if (i < EW+EC)      atomicAdd(&cntc[ei_c[EC + (i-EW)]], 1);
    else if (i < EW+EC+ER)   atomicAdd(&cntr[ei_r[ER + (i-EW-EC)]], 1);
}

// ---------------------------------------------------------------- 3 exclusive scans, shfl-based
__global__ __launch_bounds__(1024) void scan3_k(
    const int* __restrict__ c0, int n0, int* __restrict__ o0,
    const int* __restrict__ c1, int n1, int* __restrict__ o1,
    const int* __restrict__ c2, int n2, int* __restrict__ o2)
{
    __shared__ int wsum[16];
    __shared__ int carry_s;
    const int* cnt; int n; int* off;
    if (blockIdx.x == 0)      { cnt = c0; n = n0; off = o0; }
    else if (blockIdx.x == 1) { cnt = c1; n = n1; off = o1; }
    else                      { cnt = c2; n = n2; off = o2; }
    const int tid  = threadIdx.x;
    const int lane = tid & 63;
    const int wid  = tid >> 6;
    if (tid == 0) carry_s = 0;
    __syncthreads();
    const int CH = 4096;
    const int nchunk = (n + CH - 1) / CH;
    for (int c = 0; c < nchunk; ++c) {
        int base = c*CH + tid*4;
        int4 v = make_int4(0,0,0,0);
        if (base + 3 < n) v = *reinterpret_cast<const int4*>(cnt + base);
        else {
            if (base   < n) v.x = cnt[base];
            if (base+1 < n) v.y = cnt[base+1];
            if (base+2 < n) v.z = cnt[base+2];
            if (base+3 < n) v.w = cnt[base+3];
        }
        int s1 = v.x + v.y, s2 = s1 + v.z, s3 = s2 + v.w;  // thread-inclusive
        int x = s3;
#pragma unroll
        for (int d = 1; d < 64; d <<= 1) {                 // wave inclusive scan
            int u = __shfl_up(x, d, 64);
            if (lane >= d) x += u;
        }
        if (lane == 63) wsum[wid] = x;
        int texc = x - s3;                                 // exclusive within wave
        __syncthreads();
        if (wid == 0 && lane < 16) {                       // cross-wave scan (16 totals)
            int y = wsum[lane];
#pragma unroll
            for (int d = 1; d < 16; d <<= 1) {
                int u = __shfl_up(y, d, 16);
                if (lane >= d) y += u;
            }
            wsum[lane] = y;                                // inclusive
        }
        __syncthreads();
        int carry = carry_s;
        int wexc  = wid ? wsum[wid-1] : 0;
        int pre   = carry + wexc + texc;
        int4 ov = make_int4(pre, pre + v.x, pre + s1, pre + s2);
        if (base + 3 < n) *reinterpret_cast<int4*>(off + base) = ov;
        else {
            if (base   < n) off[base]   = ov.x;
            if (base+1 < n) off[base+1] = ov.y;
            if (base+2 < n) off[base+2] = ov.z;
            if (base+3 < n) off[base+3] = ov.w;
        }
        __syncthreads();
        if (tid == 0) carry_s += wsum[15];
        __syncthreads();
    }
    if (tid == 0) off[n] = carry_s;
}

// ---------------------------------------------------------------- adjacency fill (all 3; consumes cnt)
__global__ __launch_bounds__(256) void fill_all_k(
    const int* __restrict__ ei_w, const int* __restrict__ ei_c, const int* __restrict__ ei_r,
    const int* __restrict__ offw, const int* __restrict__ offc, const int* __restrict__ offr,
    int* __restrict__ cntw, int* __restrict__ cntc, int* __restrict__ cntr,
    int* __restrict__ adjw, int* __restrict__ adjc, int* __restrict__ adjr)
{
    int i = blockIdx.x * 256 + threadIdx.x;
    const int* ei; const int* off; int* cnt; int* adj; int e; int E;
    if (i < EW)            { e = i;        ei = ei_w; off = offw; cnt = cntw; adj = adjw; E = EW; }
    else if (i < EW+EC)    { e = i-EW;     ei = ei_c; off = offc; cnt = cntc; adj = adjc; E = EC; }
    else if (i < EW+EC+ER) { e = i-EW-EC;  ei = ei_r; off = offr; cnt = cntr; adj = adjr; E = ER; }
    else return;
    int d = ei[E + e];
    int p = atomicSub(&cnt[d], 1) - 1;
    adj[off[d] + p] = ei[e];
}

// ---------------------------------------------------------------- gather-mean D=128, all 3 relations
__global__ __launch_bounds__(256) void gather128_all_k(
    const float* __restrict__ x_paper, const float* __restrict__ x_author,
    const int* __restrict__ offw, const int* __restrict__ adjw, float* __restrict__ aggw,
    const int* __restrict__ offc, const int* __restrict__ adjc, float* __restrict__ aggc,
    const int* __restrict__ offr, const int* __restrict__ adjr, float* __restrict__ aggr)
{
    int W    = blockIdx.x * 4 + (threadIdx.x >> 6);
    int lane = threadIdx.x & 63;
    const float* X; const int* off; const int* adj; float* AGG; int w;
    if (W < NP)          { w = W;        X = x_author; off = offw; adj = adjw; AGG = aggw; }
    else if (W < 2*NP)   { w = W - NP;   X = x_paper;  off = offc; adj = adjc; AGG = aggc; }
    else if (W < 2*NP+NA){ w = W - 2*NP; X = x_paper;  off = offr; adj = adjr; AGG = aggr; }
    else return;
    int b = off[w], e = off[w+1];
    float2 acc = make_float2(0.f, 0.f);
    for (int j0 = b; j0 < e; j0 += 64) {
        int sl = (j0 + lane < e) ? adj[j0 + lane] : 0;
        int m  = min(64, e - j0);
        for (int k = 0; k < m; ++k) {
            int s = __shfl(sl, k, 64);
            float2 v = reinterpret_cast<const float2*>(X + (size_t)s * 128)[lane];
            acc.x += v.x; acc.y += v.y;
        }
    }
    float sc = 1.0f / fmaxf((float)(e - b), 1.0f);
    reinterpret_cast<float2*>(AGG + (size_t)w * 128)[lane] = make_float2(acc.x*sc, acc.y*sc);
}

// ---------------------------------------------------------------- fused multi-part GEMM, N=128
// C = relu?(alpha * sum_p(Ap @ Bp) + bias); reg-prefetch double buffer with
// NAMED registers only (no arrays -> nothing can demote to scratch).
// __launch_bounds__(256,1): grid is only ~391 blocks (<19% occupancy ceiling),
// so let the allocator use ~150 VGPRs for ILP instead of spilling (R10: 52 VGPR
// + 167MB scratch writes).
__device__ __forceinline__ void fma4(float4& c, float a, const float4& b) {
    c.x += a*b.x; c.y += a*b.y; c.z += a*b.z; c.w += a*b.w;
}

__global__ __launch_bounds__(256, 1) void gemmf_k(
    const float* __restrict__ A0, const float* __restrict__ A1, const float* __restrict__ A2,
    const float* __restrict__ B0, const float* __restrict__ B1, const float* __restrict__ B2,
    float* __restrict__ C, int M, int nparts, float alpha,
    const float* __restrict__ bias, int relu)
{
    __shared__ float As[32][128];   // k-major (transposed)  16 KB
    __shared__ float Bs[32][128];   // k-major (natural)     16 KB
    const int tid  = threadIdx.x;
    const int row0 = blockIdx.x * 128;
    const int tx = tid & 15;
    const int ty = tid >> 4;

    // stage-index decomposition (idx = tid + i*256; 256 ≡ 0 mod 128/32):
    const int mA  = tid & 127;          // A row within tile (constant over i)
    const int kA4 = (tid >> 7) * 4;     // A k-slot base; +8 per i
    const int n4B = tid & 31;           // B float4 column (constant over i)
    const int kB  = tid >> 5;           // B k row; +8 per i

    float4 c000 = make_float4(0,0,0,0), c001 = c000, c002 = c000, c003 = c000;
    float4 c010 = c000, c011 = c000, c012 = c000, c013 = c000;
    float4 c100 = c000, c101 = c000, c102 = c000, c103 = c000;
    float4 c110 = c000, c111 = c000, c112 = c000, c113 = c000;

    float4 ra0, ra1, ra2, ra3, rb0, rb1, rb2, rb3;
    const float4 f4z = make_float4(0,0,0,0);

    auto loadT = [&](int kt) {
        const int p  = kt >> 2;
        const int cb = (kt & 3) * 32;
        const float* Ap = (p == 0) ? A0 : (p == 1) ? A1 : A2;
        const float* Bp = (p == 0) ? B0 : (p == 1) ? B1 : B2;
        const int row = row0 + mA;
        const bool ok = row < M;
        const float* ab = Ap + (size_t)row*128 + cb + kA4;  // kA4 floats = k-slot base
        ra0 = ok ? *reinterpret_cast<const float4*>(ab +  0) : f4z;
        ra1 = ok ? *reinterpret_cast<const float4*>(ab +  8) : f4z;
        ra2 = ok ? *reinterpret_cast<const float4*>(ab + 16) : f4z;
        ra3 = ok ? *reinterpret_cast<const float4*>(ab + 24) : f4z;
        const float* bb = Bp + (size_t)(cb + kB)*128 + n4B*4;
        rb0 = *reinterpret_cast<const float4*>(bb + (size_t) 0*128);
        rb1 = *reinterpret_cast<const float4*>(bb + (size_t) 8*128);
        rb2 = *reinterpret_cast<const float4*>(bb + (size_t)16*128);
        rb3 = *reinterpret_cast<const float4*>(bb + (size_t)24*128);
    };
    auto writeT = [&]() {
        As[kA4+ 0][mA] = ra0.x; As[kA4+ 1][mA] = ra0.y; As[kA4+ 2][mA] = ra0.z; As[kA4+ 3][mA] = ra0.w;
        As[kA4+ 8][mA] = ra1.x; As[kA4+ 9][mA] = ra1.y; As[kA4+10][mA] = ra1.z; As[kA4+11][mA] = ra1.w;
        As[kA4+16][mA] = ra2.x; As[kA4+17][mA] = ra2.y; As[kA4+18][mA] = ra2.z; As[kA4+19][mA] = ra2.w;
        As[kA4+24][mA] = ra3.x; As[kA4+25][mA] = ra3.y; As[kA4+26][mA] = ra3.z; As[kA4+27][mA] = ra3.w;
        *reinterpret_cast<float4*>(&Bs[kB+ 0][n4B*4]) = rb0;
        *reinterpret_cast<float4*>(&Bs[kB+ 8][n4B*4]) = rb1;
        *reinterpret_cast<float4*>(&Bs[kB+16][n4B*4]) = rb2;
        *reinterpret_cast<float4*>(&Bs[kB+24][n4B*4]) = rb3;
    };

    const int KT = nparts * 4;
    loadT(0);
    writeT();
    __syncthreads();
    for (int kt = 0; kt < KT; ++kt) {
        if (kt + 1 < KT) loadT(kt + 1);       // global loads in flight during compute
#pragma unroll 8
        for (int k = 0; k < 32; ++k) {
            float4 a0 = *reinterpret_cast<const float4*>(&As[k][ty*4]);
            float4 a1 = *reinterpret_cast<const float4*>(&As[k][64 + ty*4]);
            float4 b0 = *reinterpret_cast<const float4*>(&Bs[k][tx*4]);
            float4 b1 = *reinterpret_cast<const float4*>(&Bs[k][64 + tx*4]);
            fma4(c000, a0.x, b0); fma4(c010, a0.x, b1);
            fma4(c001, a0.y, b0); fma4(c011, a0.y, b1);
            fma4(c002, a0.z, b0); fma4(c012, a0.z, b1);
            fma4(c003, a0.w, b0); fma4(c013, a0.w, b1);
            fma4(c100, a1.x, b0); fma4(c110, a1.x, b1);
            fma4(c101, a1.y, b0); fma4(c111, a1.y, b1);
            fma4(c102, a1.z, b0); fma4(c112, a1.z, b1);
            fma4(c103, a1.w, b0); fma4(c113, a1.w, b1);
        }
        if (kt + 1 < KT) {
            __syncthreads();
            writeT();
            __syncthreads();
        }
    }

    auto epi = [&](float4 t, int row, int col) {
        if (row >= M) return;
        float4 bb = *reinterpret_cast<const float4*>(&bias[col]);
        t.x = alpha*t.x + bb.x; t.y = alpha*t.y + bb.y;
        t.z = alpha*t.z + bb.z; t.w = alpha*t.w + bb.w;
        if (relu) {
            t.x = fmaxf(t.x, 0.f); t.y = fmaxf(t.y, 0.f);
            t.z = fmaxf(t.z, 0.f); t.w = fmaxf(t.w, 0.f);
        }
        *reinterpret_cast<float4*>(C + (size_t)row*128 + col) = t;
    };
    const int r0 = row0 + ty*4, cA = tx*4, cB = 64 + tx*4;
    epi(c000, r0+0,  cA); epi(c010, r0+0,  cB);
    epi(c001, r0+1,  cA); epi(c011, r0+1,  cB);
    epi(c002, r0+2,  cA); epi(c012, r0+2,  cB);
    epi(c003, r0+3,  cA); epi(c013, r0+3,  cB);
    epi(c100, r0+64, cA); epi(c110, r0+64, cB);
    epi(c101, r0+65, cA); epi(c111, r0+65, cB);
    epi(c102, r0+66, cA); epi(c112, r0+66, cB);
    epi(c103, r0+67, cA); epi(c113, r0+67, cB);
}

// ---------------------------------------------------------------- GEMM K=128, N=40 (single B)
__global__ __launch_bounds__(256) void gemm40_k(
    const float* __restrict__ A, const float* __restrict__ B, float* __restrict__ C, int M)
{
    __shared__ float Bs[128][40];   // 20 KB
    __shared__ float As[24][128];   // 12 KB
    const int tid  = threadIdx.x;
    const int row0 = blockIdx.x * 24;

#pragma unroll
    for (int i = 0; i < 5; ++i) {
        int idx = tid + i*256;
        reinterpret_cast<float4*>(&Bs[0][0])[idx] = reinterpret_cast<const float4*>(B)[idx];
    }
#pragma unroll
    for (int i = 0; i < 3; ++i) {
        int idx = tid + i*256;
        int r = idx >> 5, c4 = idx & 31;
        int row = row0 + r;
        float4 v = make_float4(0.f,0.f,0.f,0.f);
        if (row < M) v = reinterpret_cast<const float4*>(A + (size_t)row*128)[c4];
        reinterpret_cast<float4*>(&As[r][0])[c4] = v;
    }
    __syncthreads();

    if (tid < 240) {
        int col  = tid % 40;
        int rsub = tid / 40;
        float a0=0.f, a1=0.f, a2=0.f, a3=0.f;
        for (int k = 0; k < 128; ++k) {
            float b = Bs[k][col];
            a0 += As[rsub*4+0][k]*b;
            a1 += As[rsub*4+1][k]*b;
            a2 += As[rsub*4+2][k]*b;
            a3 += As[rsub*4+3][k]*b;
        }
        int rb = row0 + rsub*4;
        if (rb+0 < M) C[(size_t)(rb+0)*40 + col] = a0;
        if (rb+1 < M) C[(size_t)(rb+1)*40 + col] = a1;
        if (rb+2 < M) C[(size_t)(rb+2)*40 + col] = a2;
        if (rb+3 < M) C[(size_t)(rb+3)*40 + col] = a3;
    }
}

// ---------------------------------------------------------------- dual-B GEMM K=128, N=40
__global__ __launch_bounds__(256) void gemm40x2_k(
    const float* __restrict__ A, const float* __restrict__ B1, const float* __restrict__ B2,
    float* __restrict__ C1, float* __restrict__ C2, int M)
{
    __shared__ float Bs1[128][40];  // 20 KB
    __shared__ float Bs2[128][40];  // 20 KB
    __shared__ float As[24][128];   // 12 KB
    const int tid  = threadIdx.x;
    const int row0 = blockIdx.x * 24;

#pragma unroll
    for (int i = 0; i < 5; ++i) {
        int idx = tid + i*256;
        reinterpret_cast<float4*>(&Bs1[0][0])[idx] = reinterpret_cast<const float4*>(B1)[idx];
        reinterpret_cast<float4*>(&Bs2[0][0])[idx] = reinterpret_cast<const float4*>(B2)[idx];
    }
#pragma unroll
    for (int i = 0; i < 3; ++i) {
        int idx = tid + i*256;
        int r = idx >> 5, c4 = idx & 31;
        int row = row0 + r;
        float4 v = make_float4(0.f,0.f,0.f,0.f);
        if (row < M) v = reinterpret_cast<const float4*>(A + (size_t)row*128)[c4];
        reinterpret_cast<float4*>(&As[r][0])[c4] = v;
    }
    __syncthreads();

    if (tid < 240) {
        int col  = tid % 40;
        int rsub = tid / 40;
        float p0=0.f,p1=0.f,p2=0.f,p3=0.f;
        float q0=0.f,q1=0.f,q2=0.f,q3=0.f;
        for (int k = 0; k < 128; ++k) {
            float b1 = Bs1[k][col];
            float b2 = Bs2[k][col];
            float v0 = As[rsub*4+0][k], v1 = As[rsub*4+1][k];
            float v2 = As[rsub*4+2][k], v3 = As[rsub*4+3][k];
            p0 += v0*b1; p1 += v1*b1; p2 += v2*b1; p3 += v3*b1;
            q0 += v0*b2; q1 += v1*b2; q2 += v2*b2; q3 += v3*b2;
        }
        int rb = row0 + rsub*4;
        if (rb+0 < M) { C1[(size_t)(rb+0)*40 + col] = p0; C2[(size_t)(rb+0)*40 + col] = q0; }
        if (rb+1 < M) { C1[(size_t)(rb+1)*40 + col] = p1; C2[(size_t)(rb+1)*40 + col] = q1; }
        if (rb+2 < M) { C1[(size_t)(rb+2)*40 + col] = p2; C2[(size_t)(rb+2)*40 + col] = q2; }
        if (rb+3 < M) { C1[(size_t)(rb+3)*40 + col] = p3; C2[(size_t)(rb+3)*40 + col] = q3; }
    }
}

// ---------------------------------------------------------------- fused layer-1 gather + combine
__global__ __launch_bounds__(256) void gather40f_k(
    const float* __restrict__ T1w, const float* __restrict__ T1c,
    const int* __restrict__ offw, const int* __restrict__ adjw,
    const int* __restrict__ offc, const int* __restrict__ adjc,
    const float* __restrict__ b1p, float* __restrict__ out)
{
    int w    = blockIdx.x * 4 + (threadIdx.x >> 6);
    int lane = threadIdx.x & 63;
    if (w >= NP) return;
    const bool act = lane < 40;

    float aw = 0.f;
    {
        int b = offw[w], e = offw[w+1];
        for (int j0 = b; j0 < e; j0 += 64) {
            int sl = (j0 + lane < e) ? adjw[j0 + lane] : 0;
            int m  = min(64, e - j0);
            for (int k = 0; k < m; ++k) {
                int s = __shfl(sl, k, 64);
                if (act) aw += T1w[(size_t)s * 40 + lane];
            }
        }
        aw *= 1.0f / fmaxf((float)(e - b), 1.0f);
    }
    float ac = 0.f;
    {
        int b = offc[w], e = offc[w+1];
        for (int j0 = b; j0 < e; j0 += 64) {
            int sl = (j0 + lane < e) ? adjc[j0 + lane] : 0;
            int m  = min(64, e - j0);
            for (int k = 0; k < m; ++k) {
                int s = __shfl(sl, k, 64);
                if (act) ac += T1c[(size_t)s * 40 + lane];
            }
        }
        ac *= 1.0f / fmaxf((float)(e - b), 1.0f);
    }
    if (act) {
        size_t idx = (size_t)w * 40 + lane;
        out[idx] = 0.5f*(aw + ac + out[idx]) + b1p[lane];
    }
}

// ---------------------------------------------------------------- launch
extern "C" void kernel_launch(void* const* d_in, const int* in_sizes, int n_in,
                              void* d_out, int out_size, void* d_ws, size_t ws_size,
                              hipStream_t stream)
{
    (void)in_sizes; (void)n_in; (void)out_size; (void)ws_size;

    const float* x_paper  = (const float*)d_in[0];
    const float* x_author = (const float*)d_in[1];
    const int*   ei_w     = (const int*)d_in[2];
    const int*   ei_c     = (const int*)d_in[3];
    const int*   ei_r     = (const int*)d_in[4];
    const float* Wl0w = (const float*)d_in[5];
    const float* bl0w = (const float*)d_in[6];
    const float* Wr0w = (const float*)d_in[7];
    const float* Wl0c = (const float*)d_in[8];
    const float* bl0c = (const float*)d_in[9];
    const float* Wr0c = (const float*)d_in[10];
    const float* Wl0r = (const float*)d_in[11];
    const float* bl0r = (const float*)d_in[12];
    const float* Wr0r = (const float*)d_in[13];
    const float* Wl1w = (const float*)d_in[14];
    const float* bl1w = (const float*)d_in[15];
    const float* Wr1w = (const float*)d_in[16];
    const float* Wl1c = (const float*)d_in[17];
    const float* bl1c = (const float*)d_in[18];
    const float* Wr1c = (const float*)d_in[19];
    // d_in[20..22] = Wl1_r / bl1_r / Wr1_r: dead (layer-1 author output unused)
    float* out = (float*)d_out;

    float* ws = (float*)d_ws;
    size_t o = 0;
    int* cntw = (int*)(ws + o); o += NP;        // int4-aligned (NP*4 % 16 == 0)
    int* cntc = (int*)(ws + o); o += NP;
    int* cntr = (int*)(ws + o); o += NA;
    const size_t zeroInts = o;                  // memset region (cnt/cursor)
    int* offw = (int*)(ws + o); o += NP + 4;    // +4 pad keeps int4 alignment
    int* offc = (int*)(ws + o); o += NP + 4;
    int* offr = (int*)(ws + o); o += NA + 4;
    int* adjw = (int*)(ws + o); o += EW;
    int* adjc = (int*)(ws + o); o += EC;
    int* adjr = (int*)(ws + o); o += ER;
    float* aggw = ws + o; o += (size_t)NP*128;
    float* aggc = ws + o; o += (size_t)NP*128;
    float* aggr = ws + o; o += (size_t)NA*128;
    float* hp1  = ws + o; o += (size_t)NP*128;
    float* ha1  = ws + o; o += (size_t)NA*128;
    float* Wr0wc = ws + o; o += 128*128;
    float* b0p   = ws + o; o += 128;
    float* Wr1wc = ws + o; o += 128*40;
    float* b1p   = ws + o; o += 40;
    // aliases (aggw free after paper gemmf)
    float* T1w   = aggw;                 // NA*40
    float* T1c   = aggw + (size_t)NA*40; // NP*40  (2.8M floats <= NP*128)

    hipMemsetAsync(d_ws, 0, zeroInts * sizeof(int), stream);

    prep_k<<<64, 256, 0, stream>>>(Wr0w, Wr0c, bl0w, bl0c, Wr1w, Wr1c, bl1w, bl1c,
                                   Wr0wc, b0p, Wr1wc, b1p);

    // CSR build (per call; ws is re-poisoned between calls)
    count_all_k<<<(EW+EC+ER+255)/256, 256, 0, stream>>>(ei_w, ei_c, ei_r, cntw, cntc, cntr);
    scan3_k<<<3, 1024, 0, stream>>>(cntw, NP, offw, cntc, NP, offc, cntr, NA, offr);
    fill_all_k<<<(EW+EC+ER+255)/256, 256, 0, stream>>>(ei_w, ei_c, ei_r, offw, offc, offr,
                                                       cntw, cntc, cntr, adjw, adjc, adjr);

    // layer 0: gather-mean of raw features (D=128), all 3 relations, mean folded in
    gather128_all_k<<<(2*NP+NA+3)/4, 256, 0, stream>>>(x_paper, x_author,
                                                       offw, adjw, aggw,
                                                       offc, adjc, aggc,
                                                       offr, adjr, aggr);

    // hp1 = relu(0.5*(xp@Wr0wc + mw@Wl0w + mc@Wl0c) + b0p)   [K=384 fused]
    gemmf_k<<<(NP+127)/128, 256, 0, stream>>>(x_paper, aggw, aggc, Wr0wc, Wl0w, Wl0c,
                                              hp1, NP, 3, 0.5f, b0p, 1);
    // ha1 = relu(xa@Wr0r + mr@Wl0r + bl0r)                    [K=256 fused]
    gemmf_k<<<(NA+127)/128, 256, 0, stream>>>(x_author, aggr, nullptr, Wr0r, Wl0r, nullptr,
                                              ha1, NA, 2, 1.0f, bl0r, 1);

    // layer 1: transform first (40 dims), then gather
    gemm40_k  <<<(NA+23)/24, 256, 0, stream>>>(ha1, Wl1w, T1w, NA);
    gemm40x2_k<<<(NP+23)/24, 256, 0, stream>>>(hp1, Wl1c, Wr1wc, T1c, out, NP);

    // fused: out = 0.5*(mean_w(T1w) + mean_c(T1c) + out) + b1p
    gather40f_k<<<(NP+3)/4, 256, 0, stream>>>(T1w, T1c, offw, adjw, offc, adjc, b1p, out);
}

// Round 12
// 672.007 us; speedup vs baseline: 1.1157x; 1.1024x over previous
//
#include <hip/hip_runtime.h>

#define NP 50000
#define NA 20000
#define EW 400000
#define EC 800000
#define ER 400000

// ---------------------------------------------------------------- prep
__global__ __launch_bounds__(256) void prep_k(
    const float* __restrict__ Wr0w, const float* __restrict__ Wr0c,
    const float* __restrict__ bl0w, const float* __restrict__ bl0c,
    const float* __restrict__ Wr1w, const float* __restrict__ Wr1c,
    const float* __restrict__ bl1w, const float* __restrict__ bl1c,
    float* __restrict__ Wr0wc, float* __restrict__ b0p,
    float* __restrict__ Wr1wc, float* __restrict__ b1p)
{
    int i = blockIdx.x * 256 + threadIdx.x;
    if (i < 128*128) Wr0wc[i] = Wr0w[i] + Wr0c[i];
    if (i < 128*40)  Wr1wc[i] = Wr1w[i] + Wr1c[i];
    if (i < 128)     b0p[i] = 0.5f*(bl0w[i] + bl0c[i]);
    if (i < 40)      b1p[i] = 0.5f*(bl1w[i] + bl1c[i]);
}

// ---------------------------------------------------------------- degree histograms (all 3 relations)
__global__ __launch_bounds__(256) void count_all_k(
    const int* __restrict__ ei_w, const int* __restrict__ ei_c, const int* __restrict__ ei_r,
    int* __restrict__ cntw, int* __restrict__ cntc, int* __restrict__ cntr)
{
    int i = blockIdx.x * 256 + threadIdx.x;
    if (i < EW)              atomicAdd(&cntw[ei_w[EW + i]], 1);
    else if (i < EW+EC)      atomicAdd(&cntc[ei_c[EC + (i-EW)]], 1);
    else if (i < EW+EC+ER)   atomicAdd(&cntr[ei_r[ER + (i-EW-EC)]], 1);
}

// ---------------------------------------------------------------- 3 exclusive scans, shfl-based
__global__ __launch_bounds__(1024) void scan3_k(
    const int* __restrict__ c0, int n0, int* __restrict__ o0,
    const int* __restrict__ c1, int n1, int* __restrict__ o1,
    const int* __restrict__ c2, int n2, int* __restrict__ o2)
{
    __shared__ int wsum[16];
    __shared__ int carry_s;
    const int* cnt; int n; int* off;
    if (blockIdx.x == 0)      { cnt = c0; n = n0; off = o0; }
    else if (blockIdx.x == 1) { cnt = c1; n = n1; off = o1; }
    else                      { cnt = c2; n = n2; off = o2; }
    const int tid  = threadIdx.x;
    const int lane = tid & 63;
    const int wid  = tid >> 6;
    if (tid == 0) carry_s = 0;
    __syncthreads();
    const int CH = 4096;
    const int nchunk = (n + CH - 1) / CH;
    for (int c = 0; c < nchunk; ++c) {
        int base = c*CH + tid*4;
        int4 v = make_int4(0,0,0,0);
        if (base + 3 < n) v = *reinterpret_cast<const int4*>(cnt + base);
        else {
            if (base   < n) v.x = cnt[base];
            if (base+1 < n) v.y = cnt[base+1];
            if (base+2 < n) v.z = cnt[base+2];
            if (base+3 < n) v.w = cnt[base+3];
        }
        int s1 = v.x + v.y, s2 = s1 + v.z, s3 = s2 + v.w;  // thread-inclusive
        int x = s3;
#pragma unroll
        for (int d = 1; d < 64; d <<= 1) {                 // wave inclusive scan
            int u = __shfl_up(x, d, 64);
            if (lane >= d) x += u;
        }
        if (lane == 63) wsum[wid] = x;
        int texc = x - s3;                                 // exclusive within wave
        __syncthreads();
        if (wid == 0 && lane < 16) {                       // cross-wave scan (16 totals)
            int y = wsum[lane];
#pragma unroll
            for (int d = 1; d < 16; d <<= 1) {
                int u = __shfl_up(y, d, 16);
                if (lane >= d) y += u;
            }
            wsum[lane] = y;                                // inclusive
        }
        __syncthreads();
        int carry = carry_s;
        int wexc  = wid ? wsum[wid-1] : 0;
        int pre   = carry + wexc + texc;
        int4 ov = make_int4(pre, pre + v.x, pre + s1, pre + s2);
        if (base + 3 < n) *reinterpret_cast<int4*>(off + base) = ov;
        else {
            if (base   < n) off[base]   = ov.x;
            if (base+1 < n) off[base+1] = ov.y;
            if (base+2 < n) off[base+2] = ov.z;
            if (base+3 < n) off[base+3] = ov.w;
        }
        __syncthreads();
        if (tid == 0) carry_s += wsum[15];
        __syncthreads();
    }
    if (tid == 0) off[n] = carry_s;
}

// ---------------------------------------------------------------- adjacency fill (all 3; consumes cnt)
__global__ __launch_bounds__(256) void fill_all_k(
    const int* __restrict__ ei_w, const int* __restrict__ ei_c, const int* __restrict__ ei_r,
    const int* __restrict__ offw, const int* __restrict__ offc, const int* __restrict__ offr,
    int* __restrict__ cntw, int* __restrict__ cntc, int* __restrict__ cntr,
    int* __restrict__ adjw, int* __restrict__ adjc, int* __restrict__ adjr)
{
    int i = blockIdx.x * 256 + threadIdx.x;
    const int* ei; const int* off; int* cnt; int* adj; int e; int E;
    if (i < EW)            { e = i;        ei = ei_w; off = offw; cnt = cntw; adj = adjw; E = EW; }
    else if (i < EW+EC)    { e = i-EW;     ei = ei_c; off = offc; cnt = cntc; adj = adjc; E = EC; }
    else if (i < EW+EC+ER) { e = i-EW-EC;  ei = ei_r; off = offr; cnt = cntr; adj = adjr; E = ER; }
    else return;
    int d = ei[E + e];
    int p = atomicSub(&cnt[d], 1) - 1;
    adj[off[d] + p] = ei[e];
}

// ---------------------------------------------------------------- gather-mean D=128, all 3 relations
__global__ __launch_bounds__(256) void gather128_all_k(
    const float* __restrict__ x_paper, const float* __restrict__ x_author,
    const int* __restrict__ offw, const int* __restrict__ adjw, float* __restrict__ aggw,
    const int* __restrict__ offc, const int* __restrict__ adjc, float* __restrict__ aggc,
    const int* __restrict__ offr, const int* __restrict__ adjr, float* __restrict__ aggr)
{
    int W    = blockIdx.x * 4 + (threadIdx.x >> 6);
    int lane = threadIdx.x & 63;
    const float* X; const int* off; const int* adj; float* AGG; int w;
    if (W < NP)          { w = W;        X = x_author; off = offw; adj = adjw; AGG = aggw; }
    else if (W < 2*NP)   { w = W - NP;   X = x_paper;  off = offc; adj = adjc; AGG = aggc; }
    else if (W < 2*NP+NA){ w = W - 2*NP; X = x_paper;  off = offr; adj = adjr; AGG = aggr; }
    else return;
    int b = off[w], e = off[w+1];
    float2 acc = make_float2(0.f, 0.f);
    for (int j0 = b; j0 < e; j0 += 64) {
        int sl = (j0 + lane < e) ? adj[j0 + lane] : 0;
        int m  = min(64, e - j0);
        for (int k = 0; k < m; ++k) {
            int s = __shfl(sl, k, 64);
            float2 v = reinterpret_cast<const float2*>(X + (size_t)s * 128)[lane];
            acc.x += v.x; acc.y += v.y;
        }
    }
    float sc = 1.0f / fmaxf((float)(e - b), 1.0f);
    reinterpret_cast<float2*>(AGG + (size_t)w * 128)[lane] = make_float2(acc.x*sc, acc.y*sc);
}

// ---------------------------------------------------------------- fused multi-part GEMM, N=128
// REVERTED to the R5 measured-good form: direct global->LDS staging, 2 barriers
// per BK=32 tile, no reg-prefetch. Both prefetch variants (R10 arrays, R11
// named+lambdas) spilled to scratch (VGPR 52/48, 167-180MB scratch writes) and
// regressed 153-159us vs <123us for this form.
__device__ __forceinline__ void fma4(float4& c, float a, const float4& b) {
    c.x += a*b.x; c.y += a*b.y; c.z += a*b.z; c.w += a*b.w;
}

__global__ __launch_bounds__(256) void gemmf_k(
    const float* __restrict__ A0, const float* __restrict__ A1, const float* __restrict__ A2,
    const float* __restrict__ B0, const float* __restrict__ B1, const float* __restrict__ B2,
    float* __restrict__ C, int M, int nparts, float alpha,
    const float* __restrict__ bias, int relu)
{
    __shared__ float As[32][128];   // k-major (transposed)  16 KB
    __shared__ float Bs[32][128];   // k-major (natural)     16 KB
    const int tid  = threadIdx.x;
    const int row0 = blockIdx.x * 128;
    const int tx = tid & 15;
    const int ty = tid >> 4;

    float4 acc[2][2][4];
#pragma unroll
    for (int rh = 0; rh < 2; ++rh)
#pragma unroll
        for (int ch = 0; ch < 2; ++ch)
#pragma unroll
            for (int i = 0; i < 4; ++i) acc[rh][ch][i] = make_float4(0.f,0.f,0.f,0.f);

    const int KT = nparts * 4;
    for (int kt = 0; kt < KT; ++kt) {
        const int p  = kt >> 2;
        const int cb = (kt & 3) * 32;
        const float* Ap = (p == 0) ? A0 : (p == 1) ? A1 : A2;
        const float* Bp = (p == 0) ? B0 : (p == 1) ? B1 : B2;
        if (kt) __syncthreads();
        // stage A tile transposed: As[k][m]
#pragma unroll
        for (int i = 0; i < 4; ++i) {
            int idx = tid + i*256;          // 0..1023
            int m = idx & 127, kq = idx >> 7;
            int row = row0 + m;
            float4 v = make_float4(0.f,0.f,0.f,0.f);
            if (row < M) v = *reinterpret_cast<const float4*>(Ap + (size_t)row*128 + cb + kq*4);
            As[kq*4+0][m] = v.x; As[kq*4+1][m] = v.y;
            As[kq*4+2][m] = v.z; As[kq*4+3][m] = v.w;
        }
        // stage B tile: Bs[k][n]
#pragma unroll
        for (int i = 0; i < 4; ++i) {
            int idx = tid + i*256;
            int n4 = idx & 31, k = idx >> 5;
            *reinterpret_cast<float4*>(&Bs[k][n4*4]) =
                *reinterpret_cast<const float4*>(Bp + (size_t)(cb + k)*128 + n4*4);
        }
        __syncthreads();
#pragma unroll 8
        for (int k = 0; k < 32; ++k) {
            float4 a0 = *reinterpret_cast<const float4*>(&As[k][ty*4]);
            float4 a1 = *reinterpret_cast<const float4*>(&As[k][64 + ty*4]);
            float4 b0 = *reinterpret_cast<const float4*>(&Bs[k][tx*4]);
            float4 b1 = *reinterpret_cast<const float4*>(&Bs[k][64 + tx*4]);
#pragma unroll
            for (int i = 0; i < 4; ++i) {
                float av = (&a0.x)[i];
                fma4(acc[0][0][i], av, b0);
                fma4(acc[0][1][i], av, b1);
            }
#pragma unroll
            for (int i = 0; i < 4; ++i) {
                float av = (&a1.x)[i];
                fma4(acc[1][0][i], av, b0);
                fma4(acc[1][1][i], av, b1);
            }
        }
    }

#pragma unroll
    for (int rh = 0; rh < 2; ++rh)
#pragma unroll
        for (int i = 0; i < 4; ++i) {
            int row = row0 + rh*64 + ty*4 + i;
            if (row >= M) continue;
#pragma unroll
            for (int ch = 0; ch < 2; ++ch) {
                int col = ch*64 + tx*4;
                float4 t = acc[rh][ch][i];
                float4 bb = *reinterpret_cast<const float4*>(&bias[col]);
                t.x = alpha*t.x + bb.x; t.y = alpha*t.y + bb.y;
                t.z = alpha*t.z + bb.z; t.w = alpha*t.w + bb.w;
                if (relu) {
                    t.x = fmaxf(t.x, 0.f); t.y = fmaxf(t.y, 0.f);
                    t.z = fmaxf(t.z, 0.f); t.w = fmaxf(t.w, 0.f);
                }
                *reinterpret_cast<float4*>(C + (size_t)row*128 + col) = t;
            }
        }
}

// ---------------------------------------------------------------- GEMM K=128, N=40 (single B)
__global__ __launch_bounds__(256) void gemm40_k(
    const float* __restrict__ A, const float* __restrict__ B, float* __restrict__ C, int M)
{
    __shared__ float Bs[128][40];   // 20 KB
    __shared__ float As[24][128];   // 12 KB
    const int tid  = threadIdx.x;
    const int row0 = blockIdx.x * 24;

#pragma unroll
    for (int i = 0; i < 5; ++i) {
        int idx = tid + i*256;
        reinterpret_cast<float4*>(&Bs[0][0])[idx] = reinterpret_cast<const float4*>(B)[idx];
    }
#pragma unroll
    for (int i = 0; i < 3; ++i) {
        int idx = tid + i*256;
        int r = idx >> 5, c4 = idx & 31;
        int row = row0 + r;
        float4 v = make_float4(0.f,0.f,0.f,0.f);
        if (row < M) v = reinterpret_cast<const float4*>(A + (size_t)row*128)[c4];
        reinterpret_cast<float4*>(&As[r][0])[c4] = v;
    }
    __syncthreads();

    if (tid < 240) {
        int col  = tid % 40;
        int rsub = tid / 40;
        float a0=0.f, a1=0.f, a2=0.f, a3=0.f;
        for (int k = 0; k < 128; ++k) {
            float b = Bs[k][col];
            a0 += As[rsub*4+0][k]*b;
            a1 += As[rsub*4+1][k]*b;
            a2 += As[rsub*4+2][k]*b;
            a3 += As[rsub*4+3][k]*b;
        }
        int rb = row0 + rsub*4;
        if (rb+0 < M) C[(size_t)(rb+0)*40 + col] = a0;
        if (rb+1 < M) C[(size_t)(rb+1)*40 + col] = a1;
        if (rb+2 < M) C[(size_t)(rb+2)*40 + col] = a2;
        if (rb+3 < M) C[(size_t)(rb+3)*40 + col] = a3;
    }
}

// ---------------------------------------------------------------- dual-B GEMM K=128, N=40
__global__ __launch_bounds__(256) void gemm40x2_k(
    const float* __restrict__ A, const float* __restrict__ B1, const float* __restrict__ B2,
    float* __restrict__ C1, float* __restrict__ C2, int M)
{
    __shared__ float Bs1[128][40];  // 20 KB
    __shared__ float Bs2[128][40];  // 20 KB
    __shared__ float As[24][128];   // 12 KB
    const int tid  = threadIdx.x;
    const int row0 = blockIdx.x * 24;

#pragma unroll
    for (int i = 0; i < 5; ++i) {
        int idx = tid + i*256;
        reinterpret_cast<float4*>(&Bs1[0][0])[idx] = reinterpret_cast<const float4*>(B1)[idx];
        reinterpret_cast<float4*>(&Bs2[0][0])[idx] = reinterpret_cast<const float4*>(B2)[idx];
    }
#pragma unroll
    for (int i = 0; i < 3; ++i) {
        int idx = tid + i*256;
        int r = idx >> 5, c4 = idx & 31;
        int row = row0 + r;
        float4 v = make_float4(0.f,0.f,0.f,0.f);
        if (row < M) v = reinterpret_cast<const float4*>(A + (size_t)row*128)[c4];
        reinterpret_cast<float4*>(&As[r][0])[c4] = v;
    }
    __syncthreads();

    if (tid < 240) {
        int col  = tid % 40;
        int rsub = tid / 40;
        float p0=0.f,p1=0.f,p2=0.f,p3=0.f;
        float q0=0.f,q1=0.f,q2=0.f,q3=0.f;
        for (int k = 0; k < 128; ++k) {
            float b1 = Bs1[k][col];
            float b2 = Bs2[k][col];
            float v0 = As[rsub*4+0][k], v1 = As[rsub*4+1][k];
            float v2 = As[rsub*4+2][k], v3 = As[rsub*4+3][k];
            p0 += v0*b1; p1 += v1*b1; p2 += v2*b1; p3 += v3*b1;
            q0 += v0*b2; q1 += v1*b2; q2 += v2*b2; q3 += v3*b2;
        }
        int rb = row0 + rsub*4;
        if (rb+0 < M) { C1[(size_t)(rb+0)*40 + col] = p0; C2[(size_t)(rb+0)*40 + col] = q0; }
        if (rb+1 < M) { C1[(size_t)(rb+1)*40 + col] = p1; C2[(size_t)(rb+1)*40 + col] = q1; }
        if (rb+2 < M) { C1[(size_t)(rb+2)*40 + col] = p2; C2[(size_t)(rb+2)*40 + col] = q2; }
        if (rb+3 < M) { C1[(size_t)(rb+3)*40 + col] = p3; C2[(size_t)(rb+3)*40 + col] = q3; }
    }
}

// ---------------------------------------------------------------- fused layer-1 gather + combine
__global__ __launch_bounds__(256) void gather40f_k(
    const float* __restrict__ T1w, const float* __restrict__ T1c,
    const int* __restrict__ offw, const int* __restrict__ adjw,
    const int* __restrict__ offc, const int* __restrict__ adjc,
    const float* __restrict__ b1p, float* __restrict__ out)
{
    int w    = blockIdx.x * 4 + (threadIdx.x >> 6);
    int lane = threadIdx.x & 63;
    if (w >= NP) return;
    const bool act = lane < 40;

    float aw = 0.f;
    {
        int b = offw[w], e = offw[w+1];
        for (int j0 = b; j0 < e; j0 += 64) {
            int sl = (j0 + lane < e) ? adjw[j0 + lane] : 0;
            int m  = min(64, e - j0);
            for (int k = 0; k < m; ++k) {
                int s = __shfl(sl, k, 64);
                if (act) aw += T1w[(size_t)s * 40 + lane];
            }
        }
        aw *= 1.0f / fmaxf((float)(e - b), 1.0f);
    }
    float ac = 0.f;
    {
        int b = offc[w], e = offc[w+1];
        for (int j0 = b; j0 < e; j0 += 64) {
            int sl = (j0 + lane < e) ? adjc[j0 + lane] : 0;
            int m  = min(64, e - j0);
            for (int k = 0; k < m; ++k) {
                int s = __shfl(sl, k, 64);
                if (act) ac += T1c[(size_t)s * 40 + lane];
            }
        }
        ac *= 1.0f / fmaxf((float)(e - b), 1.0f);
    }
    if (act) {
        size_t idx = (size_t)w * 40 + lane;
        out[idx] = 0.5f*(aw + ac + out[idx]) + b1p[lane];
    }
}

// ---------------------------------------------------------------- launch
extern "C" void kernel_launch(void* const* d_in, const int* in_sizes, int n_in,
                              void* d_out, int out_size, void* d_ws, size_t ws_size,
                              hipStream_t stream)
{
    (void)in_sizes; (void)n_in; (void)out_size; (void)ws_size;

    const float* x_paper  = (const float*)d_in[0];
    const float* x_author = (const float*)d_in[1];
    const int*   ei_w     = (const int*)d_in[2];
    const int*   ei_c     = (const int*)d_in[3];
    const int*   ei_r     = (const int*)d_in[4];
    const float* Wl0w = (const float*)d_in[5];
    const float* bl0w = (const float*)d_in[6];
    const float* Wr0w = (const float*)d_in[7];
    const float* Wl0c = (const float*)d_in[8];
    const float* bl0c = (const float*)d_in[9];
    const float* Wr0c = (const float*)d_in[10];
    const float* Wl0r = (const float*)d_in[11];
    const float* bl0r = (const float*)d_in[12];
    const float* Wr0r = (const float*)d_in[13];
    const float* Wl1w = (const float*)d_in[14];
    const float* bl1w = (const float*)d_in[15];
    const float* Wr1w = (const float*)d_in[16];
    const float* Wl1c = (const float*)d_in[17];
    const float* bl1c = (const float*)d_in[18];
    const float* Wr1c = (const float*)d_in[19];
    // d_in[20..22] = Wl1_r / bl1_r / Wr1_r: dead (layer-1 author output unused)
    float* out = (float*)d_out;

    float* ws = (float*)d_ws;
    size_t o = 0;
    int* cntw = (int*)(ws + o); o += NP;        // int4-aligned (NP*4 % 16 == 0)
    int* cntc = (int*)(ws + o); o += NP;
    int* cntr = (int*)(ws + o); o += NA;
    const size_t zeroInts = o;                  // memset region (cnt/cursor)
    int* offw = (int*)(ws + o); o += NP + 4;    // +4 pad keeps int4 alignment
    int* offc = (int*)(ws + o); o += NP + 4;
    int* offr = (int*)(ws + o); o += NA + 4;
    int* adjw = (int*)(ws + o); o += EW;
    int* adjc = (int*)(ws + o); o += EC;
    int* adjr = (int*)(ws + o); o += ER;
    float* aggw = ws + o; o += (size_t)NP*128;
    float* aggc = ws + o; o += (size_t)NP*128;
    float* aggr = ws + o; o += (size_t)NA*128;
    float* hp1  = ws + o; o += (size_t)NP*128;
    float* ha1  = ws + o; o += (size_t)NA*128;
    float* Wr0wc = ws + o; o += 128*128;
    float* b0p   = ws + o; o += 128;
    float* Wr1wc = ws + o; o += 128*40;
    float* b1p   = ws + o; o += 40;
    // aliases (aggw free after paper gemmf)
    float* T1w   = aggw;                 // NA*40
    float* T1c   = aggw + (size_t)NA*40; // NP*40  (2.8M floats <= NP*128)

    hipMemsetAsync(d_ws, 0, zeroInts * sizeof(int), stream);

    prep_k<<<64, 256, 0, stream>>>(Wr0w, Wr0c, bl0w, bl0c, Wr1w, Wr1c, bl1w, bl1c,
                                   Wr0wc, b0p, Wr1wc, b1p);

    // CSR build (per call; ws is re-poisoned between calls)
    count_all_k<<<(EW+EC+ER+255)/256, 256, 0, stream>>>(ei_w, ei_c, ei_r, cntw, cntc, cntr);
    scan3_k<<<3, 1024, 0, stream>>>(cntw, NP, offw, cntc, NP, offc, cntr, NA, offr);
    fill_all_k<<<(EW+EC+ER+255)/256, 256, 0, stream>>>(ei_w, ei_c, ei_r, offw, offc, offr,
                                                       cntw, cntc, cntr, adjw, adjc, adjr);

    // layer 0: gather-mean of raw features (D=128), all 3 relations, mean folded in
    gather128_all_k<<<(2*NP+NA+3)/4, 256, 0, stream>>>(x_paper, x_author,
                                                       offw, adjw, aggw,
                                                       offc, adjc, aggc,
                                                       offr, adjr, aggr);

    // hp1 = relu(0.5*(xp@Wr0wc + mw@Wl0w + mc@Wl0c) + b0p)   [K=384 fused]
    gemmf_k<<<(NP+127)/128, 256, 0, stream>>>(x_paper, aggw, aggc, Wr0wc, Wl0w, Wl0c,
                                              hp1, NP, 3, 0.5f, b0p, 1);
    // ha1 = relu(xa@Wr0r + mr@Wl0r + bl0r)                    [K=256 fused]
    gemmf_k<<<(NA+127)/128, 256, 0, stream>>>(x_author, aggr, nullptr, Wr0r, Wl0r, nullptr,
                                              ha1, NA, 2, 1.0f, bl0r, 1);

    // layer 1: transform first (40 dims), then gather
    gemm40_k  <<<(NA+23)/24, 256, 0, stream>>>(ha1, Wl1w, T1w, NA);
    gemm40x2_k<<<(NP+23)/24, 256, 0, stream>>>(hp1, Wl1c, Wr1wc, T1c, out, NP);

    // fused: out = 0.5*(mean_w(T1w) + mean_c(T1c) + out) + b1p
    gather40f_k<<<(NP+3)/4, 256, 0, stream>>>(T1w, T1c, offw, adjw, offc, adjc, b1p, out);
}